// Round 1
// baseline (207.024 us; speedup 1.0000x reference)
//
#include <hip/hip_runtime.h>
#include <cfloat>
#include <cmath>

// PillarEncoder fused kernel (MI355X / gfx950)
// out[b][c][y][x], shape (4, 64, 496, 432) fp32
#define XL 432
#define YL 496
#define NCH 64
#define HIMG 192
#define WIMG 640
#define PTS_M 32

#define WAVES 8   // waves per block (512 threads)
#define PPG 4     // pillars per group per wave
#define NBLOCKS 256
#define TPB 512

__global__ __launch_bounds__(TPB, 1) void pillar_fused(
    const float* __restrict__ pillars,   // P*32*4
    const int*   __restrict__ coors,     // P*3  (b, ix, iy)
    const int*   __restrict__ npp,       // P
    const float* __restrict__ image,     // B*64*192*640
    const float* __restrict__ calibs,    // B*3*4
    const float* __restrict__ conv_w,    // 64*9
    const float* __restrict__ bng, const float* __restrict__ bnb,
    const float* __restrict__ bnm, const float* __restrict__ bnv,
    const float* __restrict__ w1, const float* __restrict__ b1,   // 128x128, 128
    const float* __restrict__ lng, const float* __restrict__ lnb, // 128
    const float* __restrict__ w2, const float* __restrict__ b2,   // 64x128, 64
    float* __restrict__ out, int P)
{
    // transposed weights: w1t[k*128 + j] = w1[j][k]; w2t[k*64 + c] = w2[c][k]
    __shared__ float w1t[128 * 128];          // 64 KB
    __shared__ float w2t[128 * 64];           // 32 KB
    __shared__ float catL[WAVES][PPG][128];   // 16 KB  [pool(64) | img(64)]
    __shared__ float gL[WAVES][PPG][128];     // 16 KB

    const int tid = threadIdx.x;
    const int lane = tid & 63;
    const int wv = tid >> 6;

    for (int i = tid; i < 128 * 128; i += TPB) {
        const int j = i >> 7, k = i & 127;
        w1t[k * 128 + j] = w1[i];
    }
    for (int i = tid; i < 128 * 64; i += TPB) {
        const int c = i >> 7, k = i & 127;
        w2t[k * 64 + c] = w2[i];
    }
    __syncthreads();

    // per-channel (lane = channel) constants; conv folded:
    // feat = [x_off,y_off,z,r,ox,oy,oz,x_off,y_off] =>
    // h = x*(w0+w4+w7) + y*(w1+w5+w8) + z*(w2+w6) + r*w3
    //     - cx*(w0+w7) - cy*(w1+w8) - mx*w4 - my*w5 - mz*w6
    // BN affine folded into all coefficients (scale s, offset tch).
    float cw[9];
    #pragma unroll
    for (int i = 0; i < 9; ++i) cw[i] = conv_w[lane * 9 + i];
    const float s   = bng[lane] / sqrtf(bnv[lane] + 1e-3f);
    const float tch = bnb[lane] - bnm[lane] * s;   // BN(0) — value of masked rows
    const float As = (cw[0] + cw[4] + cw[7]) * s;
    const float Bs = (cw[1] + cw[5] + cw[8]) * s;
    const float Cs = (cw[2] + cw[6]) * s;
    const float Ds = cw[3] * s;
    const float w07 = (cw[0] + cw[7]) * s;
    const float w18 = (cw[1] + cw[8]) * s;
    const float w4s = cw[4] * s, w5s = cw[5] * s, w6s = cw[6] * s;

    const float b1a = b1[lane], b1b = b1[lane + 64];
    const float lga = lng[lane], lgb = lng[lane + 64];
    const float lba = lnb[lane], lbb = lnb[lane + 64];
    const float gb2 = b2[lane];

    const int ngroups = (P + PPG - 1) / PPG;
    const int gstride = gridDim.x * WAVES;

    for (int grp = blockIdx.x * WAVES + wv; grp < ngroups; grp += gstride) {
        const int pbase = grp * PPG;

        // ---------- encode 4 pillars -> catL ----------
        #pragma unroll
        for (int pp = 0; pp < PPG; ++pp) {
            const int p = pbase + pp;
            if (p >= P) {
                catL[wv][pp][lane] = 0.f;
                catL[wv][pp][lane + 64] = 0.f;
                continue;
            }
            const int bb = coors[p * 3];
            const int n = npp[p];
            const float fn = (float)n;

            // mean of xyz: invalid points are already zeroed in the data
            float4 pt = make_float4(0.f, 0.f, 0.f, 0.f);
            if (lane < PTS_M) pt = ((const float4*)pillars)[p * PTS_M + lane];
            float sx = pt.x, sy = pt.y, sz = pt.z;
            #pragma unroll
            for (int d = 32; d; d >>= 1) {
                sx += __shfl_xor(sx, d);
                sy += __shfl_xor(sy, d);
                sz += __shfl_xor(sz, d);
            }
            const float mx = sx / fn, my = sy / fn, mz = sz / fn;

            // camera projection (uniform across lanes)
            const float* cb = calibs + bb * 12;
            const float pr0 = cb[0]*mx + cb[1]*my + cb[2]*mz + cb[3];
            const float pr1 = cb[4]*mx + cb[5]*my + cb[6]*mz + cb[7];
            const float pr2 = cb[8]*mx + cb[9]*my + cb[10]*mz + cb[11];
            float uf = (pr0 / pr2) * 0.5f;
            float vf = (pr1 / pr2) * 0.5f;
            uf = fminf(fmaxf(uf, 0.f), (float)(WIMG - 1));
            vf = fminf(fmaxf(vf, 0.f), (float)(HIMG - 1));
            const int u = (int)uf, v = (int)vf;

            const float cxp = (float)coors[p * 3 + 1] * 0.16f + 0.08f;
            const float cyp = (float)coors[p * 3 + 2] * 0.16f + (-39.6f);
            const float Es = tch - (cxp * w07 + cyp * w18 + mx * w4s + my * w5s + mz * w6s);

            // masked rows (m >= n) contribute BN(0)=tch to the max
            float pooled = (n < PTS_M) ? tch : -FLT_MAX;
            const float4* pb = (const float4*)pillars + p * PTS_M;
            for (int m = 0; m < n; ++m) {
                const float4 q = pb[m];   // uniform address -> scalar load path
                const float h = Es + q.x * As + q.y * Bs + q.z * Cs + q.w * Ds;
                pooled = fmaxf(pooled, h);
            }
            pooled = fmaxf(pooled, 0.f);  // relu commutes with max

            const float img = image[(((bb * NCH) + lane) * HIMG + v) * WIMG + u];
            catL[wv][pp][lane] = pooled;
            catL[wv][pp][lane + 64] = img;
        }
        asm volatile("s_waitcnt lgkmcnt(0)" ::: "memory");  // wave-private LDS handoff

        // ---------- GEMM1: g[j] = b1[j] + sum_k cat[k]*w1[j][k] ----------
        float accA[PPG], accB[PPG];
        #pragma unroll
        for (int pp = 0; pp < PPG; ++pp) { accA[pp] = b1a; accB[pp] = b1b; }

        #pragma unroll 4
        for (int k = 0; k < 128; ++k) {
            const float wa = w1t[k * 128 + lane];        // 2-way bank alias: free
            const float wb = w1t[k * 128 + lane + 64];
            #pragma unroll
            for (int pp = 0; pp < PPG; ++pp) {
                const float cv = catL[wv][pp][k];        // same-addr broadcast
                accA[pp] += cv * wa;
                accB[pp] += cv * wb;
            }
        }

        // ---------- LayerNorm(128) + relu ----------
        float sum[PPG], sq[PPG];
        #pragma unroll
        for (int pp = 0; pp < PPG; ++pp) {
            sum[pp] = accA[pp] + accB[pp];
            sq[pp]  = accA[pp] * accA[pp] + accB[pp] * accB[pp];
        }
        #pragma unroll
        for (int d = 32; d; d >>= 1) {
            #pragma unroll
            for (int pp = 0; pp < PPG; ++pp) {
                sum[pp] += __shfl_xor(sum[pp], d);
                sq[pp]  += __shfl_xor(sq[pp], d);
            }
        }
        #pragma unroll
        for (int pp = 0; pp < PPG; ++pp) {
            const float mu  = sum[pp] * (1.f / 128.f);
            const float var = sq[pp] * (1.f / 128.f) - mu * mu;
            const float inv = 1.f / sqrtf(var + 1e-5f);
            float g0 = (accA[pp] - mu) * inv * lga + lba;
            float g1 = (accB[pp] - mu) * inv * lgb + lbb;
            gL[wv][pp][lane]      = fmaxf(g0, 0.f);
            gL[wv][pp][lane + 64] = fmaxf(g1, 0.f);
        }
        asm volatile("s_waitcnt lgkmcnt(0)" ::: "memory");

        // ---------- GEMM2 + sigmoid gate + blend + scatter ----------
        float ac2[PPG];
        #pragma unroll
        for (int pp = 0; pp < PPG; ++pp) ac2[pp] = gb2;
        #pragma unroll 4
        for (int k = 0; k < 128; ++k) {
            const float w = w2t[k * 64 + lane];
            #pragma unroll
            for (int pp = 0; pp < PPG; ++pp) ac2[pp] += gL[wv][pp][k] * w;
        }

        #pragma unroll
        for (int pp = 0; pp < PPG; ++pp) {
            const int p = pbase + pp;
            if (p >= P) continue;
            const float gate = 1.f / (1.f + expf(-ac2[pp]));
            const float pooled = catL[wv][pp][lane];
            const float img    = catL[wv][pp][lane + 64];
            const float gf = pooled * gate + img * (1.f - gate);
            const int bb  = coors[p * 3];
            const int ixx = coors[p * 3 + 1];
            const int iyy = coors[p * 3 + 2];
            out[(((bb * NCH) + lane) * YL + iyy) * XL + ixx] = gf;
        }
    }
}

extern "C" void kernel_launch(void* const* d_in, const int* in_sizes, int n_in,
                              void* d_out, int out_size, void* d_ws, size_t ws_size,
                              hipStream_t stream)
{
    const float* pillars = (const float*)d_in[0];
    const int*   coors   = (const int*)d_in[1];
    const int*   npp     = (const int*)d_in[2];
    const float* image   = (const float*)d_in[3];
    const float* calibs  = (const float*)d_in[4];
    // d_in[5] = batch_size (unused; geometry fixed by setup)
    const float* conv_w  = (const float*)d_in[6];
    const float* bng     = (const float*)d_in[7];
    const float* bnb     = (const float*)d_in[8];
    const float* bnm     = (const float*)d_in[9];
    const float* bnv     = (const float*)d_in[10];
    const float* w1      = (const float*)d_in[11];
    const float* b1      = (const float*)d_in[12];
    const float* lng     = (const float*)d_in[13];
    const float* lnb     = (const float*)d_in[14];
    const float* w2      = (const float*)d_in[15];
    const float* b2      = (const float*)d_in[16];
    float* out = (float*)d_out;
    const int P = in_sizes[0] / (PTS_M * 4);

    hipMemsetAsync(d_out, 0, (size_t)out_size * sizeof(float), stream);
    pillar_fused<<<dim3(NBLOCKS), dim3(TPB), 0, stream>>>(
        pillars, coors, npp, image, calibs, conv_w, bng, bnb, bnm, bnv,
        w1, b1, lng, lnb, w2, b2, out, P);
}